// Round 11
// baseline (913.555 us; speedup 1.0000x reference)
//
#include <hip/hip_runtime.h>
#include <hip/hip_fp16.h>
#include <cstdint>
#include <cstddef>

// GCNII: h0 = relu(x@W_in + b_in); 8x { s = .9*Ahat@h + .1*h0; h = relu(s @ Wl) };
// out = h@W_out + b_out.  Ahat = D^-1/2 (A + I) D^-1/2 (deg over targets, +1 self loop).
// Activations fp16; weights transposed to fp16 once; MFMA f16 GEMMs (fp32 accum).
// PRESCALE: layers propagate g = dinv .* h (scaled in GEMM epilogue), so aggregation is
//   agg = di*(g[node] + sum g[src]) — no per-edge weight loads.  [exact algebra]
// BISECT NOTE (r9/r10 fails at absmax~0.138): NT builtins were NOT the bug (r10 disproved).
//   Remaining suspects: 16-lane/f16x8 agg rewrite vs prescale+WS. This round = r8's exact
//   32-lane/f16x4 agg text + prescale only. Pass => agg rewrite guilty; fail => prescale.
// CSR build: LDS-privatized radix partition (r8).
// Aggregation standalone + LDS-free (latency-bound; r4 fusion lesson).

#define HID 128
#define BKSH 9                 // bucket = dst >> 9  (512 nodes per bucket)
#define RMAX 256               // LDS array bound (R = ceil(N/512) = 196 for N=100k)
#define SLICE_CAP 11264        // partB LDS slice entries (E/R ~ 8163, +30% headroom)

using f16x8 = __attribute__((ext_vector_type(8))) _Float16;
using f16x4 = __attribute__((ext_vector_type(4))) _Float16;
using f32x4 = __attribute__((ext_vector_type(4))) float;

// ---------------- CSR build: radix partition ----------------

__global__ __launch_bounds__(512) void k_bhist(const int* __restrict__ col, int E,
                                               int* __restrict__ bcnt, int R) {
  __shared__ int lh[RMAX];
  int tid = threadIdx.x;
  if (tid < R) lh[tid] = 0;
  __syncthreads();
  int base = blockIdx.x * 4096;
#pragma unroll
  for (int i = 0; i < 8; ++i) {
    int e = base + i * 512 + tid;
    if (e < E) atomicAdd(&lh[col[e] >> BKSH], 1);
  }
  __syncthreads();
  if (tid < R && lh[tid]) atomicAdd(&bcnt[tid], lh[tid]);
}

__global__ __launch_bounds__(256) void k_scan196(const int* __restrict__ bcnt,
                                                 int* __restrict__ gb,
                                                 int* __restrict__ gfront, int R) {
  __shared__ int s[256];
  int t = threadIdx.x;
  int v = (t < R) ? bcnt[t] : 0;
  s[t] = v;
  __syncthreads();
  for (int off = 1; off < 256; off <<= 1) {
    int a = (t >= off) ? s[t - off] : 0;
    __syncthreads();
    s[t] += a;
    __syncthreads();
  }
  int excl = s[t] - v;
  if (t < R) {
    gb[t] = excl;
    gfront[t] = excl;
  }
  if (t == 255) gb[R] = s[255];
}

__global__ __launch_bounds__(512) void k_partA(const int* __restrict__ row,
                                               const int* __restrict__ col, int E,
                                               int* __restrict__ gfront,
                                               int* __restrict__ tmp, int R) {
  __shared__ int lh[RMAX], base[RMAX], fr[RMAX];
  int tid = threadIdx.x;
  if (tid < R) { lh[tid] = 0; fr[tid] = 0; }
  __syncthreads();
  int b0 = blockIdx.x * 4096;
  int r[8], c[8], bk[8];
  bool ok[8];
#pragma unroll
  for (int i = 0; i < 8; ++i) {
    int e = b0 + i * 512 + tid;
    ok[i] = e < E;
    if (ok[i]) {
      r[i] = row[e];
      c[i] = col[e];
      bk[i] = c[i] >> BKSH;
      atomicAdd(&lh[bk[i]], 1);
    }
  }
  __syncthreads();
  if (tid < R && lh[tid] > 0) base[tid] = atomicAdd(&gfront[tid], lh[tid]);
  __syncthreads();
#pragma unroll
  for (int i = 0; i < 8; ++i) {
    if (ok[i]) {
      int o = atomicAdd(&fr[bk[i]], 1);
      tmp[base[bk[i]] + o] = (r[i] << BKSH) | (c[i] & ((1 << BKSH) - 1));
    }
  }
}

// per-bucket LDS counting sort -> csr_src (coalesced), row_ptr, dinv
__global__ __launch_bounds__(512) void k_partB(const int* __restrict__ tmp,
                                               const int* __restrict__ gb,
                                               int* __restrict__ csr_src,
                                               int* __restrict__ row_ptr,
                                               float* __restrict__ dinv, int N, int E,
                                               int R) {
  __shared__ int h2[512], pref[512];
  __shared__ int slice[SLICE_CAP];
  int tid = threadIdx.x;
  int b = blockIdx.x;
  int lo = gb[b], hi = gb[b + 1];
  int cnt = hi - lo;
  h2[tid] = 0;
  __syncthreads();
  for (int k = tid; k < cnt; k += 512) atomicAdd(&h2[tmp[lo + k] & 511], 1);
  __syncthreads();
  int v = h2[tid];
  pref[tid] = v;
  __syncthreads();
  for (int off = 1; off < 512; off <<= 1) {
    int a = (tid >= off) ? pref[tid - off] : 0;
    __syncthreads();
    pref[tid] += a;
    __syncthreads();
  }
  int excl = pref[tid] - v;
  int node = b * 512 + tid;
  if (node < N) {
    row_ptr[node] = lo + excl;
    dinv[node] = rsqrtf((float)v + 1.0f);  // +1 self loop
  }
  if (b == R - 1 && tid == 0) row_ptr[N] = E;
  __syncthreads();
  pref[tid] = excl;
  h2[tid] = 0;
  __syncthreads();
  for (int k = tid; k < cnt; k += 512) {
    int ent = tmp[lo + k];
    int nd = ent & 511;
    int o = pref[nd] + atomicAdd(&h2[nd], 1);
    if (o < SLICE_CAP) slice[o] = ent >> BKSH;
    else csr_src[lo + o] = ent >> BKSH;  // overflow fallback (never for this data)
  }
  __syncthreads();
  int lim = cnt < SLICE_CAP ? cnt : SLICE_CAP;
  for (int k = tid; k < lim; k += 512) csr_src[lo + k] = slice[k];
}

// ---------------- weight prep ----------------
// Wt layout: [L x (128x128)] [W_in (128x128)] [W_out (64x128)]; each stored [n][k].
__global__ void k_wprep(const float* __restrict__ Wc, const float* __restrict__ W_in,
                        const float* __restrict__ W_out, _Float16* __restrict__ Wt,
                        int L) {
  int id = blockIdx.x * blockDim.x + threadIdx.x;
  int nl = L * 16384;
  if (id < nl) {
    int l = id >> 14, r = id & 16383;
    int k = r >> 7, n = r & 127;
    Wt[(size_t)l * 16384 + n * 128 + k] = (_Float16)Wc[(size_t)l * 16384 + k * 128 + n];
  } else if (id < nl + 16384) {
    int r = id - nl;
    int k = r >> 7, n = r & 127;
    Wt[(size_t)nl + n * 128 + k] = (_Float16)W_in[k * 128 + n];
  } else if (id < nl + 16384 + 8192) {
    int r = id - nl - 16384;
    int k = r >> 6, n = r & 63;
    Wt[(size_t)(nl + 16384) + n * 128 + k] = (_Float16)W_out[k * 64 + n];
  }
}

// ---------------- aggregation (r8 structure exactly; prescale removes dinv gathers) ----
// support[node] = .9*di*(g[node] + sum g[src]) + .1*x0[node],  g = dinv .* h prescaled.
// 32 lanes per node (lane owns dims [4*lane,4*lane+4), one 8B f16x4 load per row),
// 2 nodes per wave, unroll 8 -> 16 independent row gathers in flight per wave.

__global__ __launch_bounds__(256) void k_aggregate(
    const _Float16* __restrict__ g, const _Float16* __restrict__ x0h,
    const float* __restrict__ dinv, const int* __restrict__ row_ptr,
    const int* __restrict__ csr_src, _Float16* __restrict__ support, int N) {
  int node = blockIdx.x * 8 + (threadIdx.x >> 5);
  if (node >= N) return;
  int lane = threadIdx.x & 31;
  int d0 = lane * 4;
  int beg = row_ptr[node], end = row_ptr[node + 1];
  float di = dinv[node];

  f16x4 v0 = *(const f16x4*)(g + (size_t)node * HID + d0);
  f16x4 xv = *(const f16x4*)(x0h + (size_t)node * HID + d0);

  float a0 = (float)v0[0], a1 = (float)v0[1];
  float a2 = (float)v0[2], a3 = (float)v0[3];

  int j = beg;
  for (; j + 8 <= end; j += 8) {
    int s0 = csr_src[j],     s1 = csr_src[j + 1], s2 = csr_src[j + 2], s3 = csr_src[j + 3];
    int s4 = csr_src[j + 4], s5 = csr_src[j + 5], s6 = csr_src[j + 6], s7 = csr_src[j + 7];
    f16x4 r0 = *(const f16x4*)(g + (size_t)s0 * HID + d0);
    f16x4 r1 = *(const f16x4*)(g + (size_t)s1 * HID + d0);
    f16x4 r2 = *(const f16x4*)(g + (size_t)s2 * HID + d0);
    f16x4 r3 = *(const f16x4*)(g + (size_t)s3 * HID + d0);
    f16x4 r4 = *(const f16x4*)(g + (size_t)s4 * HID + d0);
    f16x4 r5 = *(const f16x4*)(g + (size_t)s5 * HID + d0);
    f16x4 r6 = *(const f16x4*)(g + (size_t)s6 * HID + d0);
    f16x4 r7 = *(const f16x4*)(g + (size_t)s7 * HID + d0);
    a0 += (float)r0[0] + (float)r1[0] + (float)r2[0] + (float)r3[0] +
          (float)r4[0] + (float)r5[0] + (float)r6[0] + (float)r7[0];
    a1 += (float)r0[1] + (float)r1[1] + (float)r2[1] + (float)r3[1] +
          (float)r4[1] + (float)r5[1] + (float)r6[1] + (float)r7[1];
    a2 += (float)r0[2] + (float)r1[2] + (float)r2[2] + (float)r3[2] +
          (float)r4[2] + (float)r5[2] + (float)r6[2] + (float)r7[2];
    a3 += (float)r0[3] + (float)r1[3] + (float)r2[3] + (float)r3[3] +
          (float)r4[3] + (float)r5[3] + (float)r6[3] + (float)r7[3];
  }
  if (j + 4 <= end) {
    int s0 = csr_src[j], s1 = csr_src[j + 1], s2 = csr_src[j + 2], s3 = csr_src[j + 3];
    f16x4 r0 = *(const f16x4*)(g + (size_t)s0 * HID + d0);
    f16x4 r1 = *(const f16x4*)(g + (size_t)s1 * HID + d0);
    f16x4 r2 = *(const f16x4*)(g + (size_t)s2 * HID + d0);
    f16x4 r3 = *(const f16x4*)(g + (size_t)s3 * HID + d0);
    a0 += (float)r0[0] + (float)r1[0] + (float)r2[0] + (float)r3[0];
    a1 += (float)r0[1] + (float)r1[1] + (float)r2[1] + (float)r3[1];
    a2 += (float)r0[2] + (float)r1[2] + (float)r2[2] + (float)r3[2];
    a3 += (float)r0[3] + (float)r1[3] + (float)r2[3] + (float)r3[3];
    j += 4;
  }
  for (; j < end; ++j) {
    int s = csr_src[j];
    f16x4 r = *(const f16x4*)(g + (size_t)s * HID + d0);
    a0 += (float)r[0]; a1 += (float)r[1]; a2 += (float)r[2]; a3 += (float)r[3];
  }
  float s9 = 0.9f * di;
  f16x4 o;
  o[0] = (_Float16)(s9 * a0 + 0.1f * (float)xv[0]);
  o[1] = (_Float16)(s9 * a1 + 0.1f * (float)xv[1]);
  o[2] = (_Float16)(s9 * a2 + 0.1f * (float)xv[2]);
  o[3] = (_Float16)(s9 * a3 + 0.1f * (float)xv[3]);
  *(f16x4*)(support + (size_t)node * HID + d0) = o;
}

// ---------------- MFMA GEMM: op(A[M][128] @ W), Bt = W^T fp16 [NC][128] ----------------
// r8 epilogue text + one added WS store.  WS: also write Cs = dinv.*result (fp16).
// WR: write raw result (fp16 if OHALF else fp32).

template <int NC, bool RELU, bool BIAS, bool AF32, bool OHALF, bool WS, bool WR>
__global__ __launch_bounds__(256) void k_mfma_gemm(const void* __restrict__ Av,
                                                   const _Float16* __restrict__ Bt,
                                                   const float* __restrict__ bias,
                                                   const float* __restrict__ dinv,
                                                   _Float16* __restrict__ Cs,
                                                   void* __restrict__ Craw, int M) {
  constexpr int NT = NC / 16;
  int tid = threadIdx.x;
  int w = tid >> 6, l = tid & 63;
  int lm = l & 15, kg = l >> 4;
  int row0 = blockIdx.x * 128 + w * 32;
  int r0 = min(row0 + lm, M - 1);        // clamp: values unused for r>=M (stores guarded)
  int r1 = min(row0 + 16 + lm, M - 1);

  f32x4 acc[2][NT];
#pragma unroll
  for (int mt = 0; mt < 2; ++mt)
#pragma unroll
    for (int nt = 0; nt < NT; ++nt) acc[mt][nt] = (f32x4){0.f, 0.f, 0.f, 0.f};

#pragma unroll
  for (int ks = 0; ks < 128; ks += 32) {
    f16x8 a0, a1;
    if (AF32) {
      const float* Af = (const float*)Av;
      float4 p0 = *(const float4*)(Af + (size_t)r0 * 128 + ks + kg * 8);
      float4 p1 = *(const float4*)(Af + (size_t)r0 * 128 + ks + kg * 8 + 4);
      float4 q0 = *(const float4*)(Af + (size_t)r1 * 128 + ks + kg * 8);
      float4 q1 = *(const float4*)(Af + (size_t)r1 * 128 + ks + kg * 8 + 4);
      a0[0] = (_Float16)p0.x; a0[1] = (_Float16)p0.y; a0[2] = (_Float16)p0.z; a0[3] = (_Float16)p0.w;
      a0[4] = (_Float16)p1.x; a0[5] = (_Float16)p1.y; a0[6] = (_Float16)p1.z; a0[7] = (_Float16)p1.w;
      a1[0] = (_Float16)q0.x; a1[1] = (_Float16)q0.y; a1[2] = (_Float16)q0.z; a1[3] = (_Float16)q0.w;
      a1[4] = (_Float16)q1.x; a1[5] = (_Float16)q1.y; a1[6] = (_Float16)q1.z; a1[7] = (_Float16)q1.w;
    } else {
      const _Float16* Ah = (const _Float16*)Av;
      a0 = *(const f16x8*)(Ah + (size_t)r0 * 128 + ks + kg * 8);
      a1 = *(const f16x8*)(Ah + (size_t)r1 * 128 + ks + kg * 8);
    }
#pragma unroll
    for (int nt = 0; nt < NT; ++nt) {
      f16x8 b = *(const f16x8*)(Bt + (size_t)(nt * 16 + lm) * 128 + ks + kg * 8);
      acc[0][nt] = __builtin_amdgcn_mfma_f32_16x16x32_f16(a0, b, acc[0][nt], 0, 0, 0);
      acc[1][nt] = __builtin_amdgcn_mfma_f32_16x16x32_f16(a1, b, acc[1][nt], 0, 0, 0);
    }
  }

#pragma unroll
  for (int mt = 0; mt < 2; ++mt) {
#pragma unroll
    for (int nt = 0; nt < NT; ++nt) {
      int colc = nt * 16 + lm;
      float bv = BIAS ? bias[colc] : 0.0f;
#pragma unroll
      for (int i = 0; i < 4; ++i) {
        int r = row0 + mt * 16 + kg * 4 + i;
        if (r >= M) continue;
        float v = acc[mt][nt][i] + bv;
        if (RELU) v = fmaxf(v, 0.0f);
        if (WR) {
          if (OHALF)
            ((_Float16*)Craw)[(size_t)r * NC + colc] = (_Float16)v;
          else
            ((float*)Craw)[(size_t)r * NC + colc] = v;
        }
        if (WS) Cs[(size_t)r * NC + colc] = (_Float16)(dinv[r] * v);
      }
    }
  }
}

// ---------------- launch ----------------

extern "C" void kernel_launch(void* const* d_in, const int* in_sizes, int n_in,
                              void* d_out, int out_size, void* d_ws, size_t ws_size,
                              hipStream_t stream) {
  const float* x     = (const float*)d_in[0];
  const int*   ei    = (const int*)d_in[1];
  const float* W_in  = (const float*)d_in[2];
  const float* b_in  = (const float*)d_in[3];
  const float* Wc    = (const float*)d_in[4];
  const float* W_out = (const float*)d_in[5];
  const float* b_out = (const float*)d_in[6];
  float* out = (float*)d_out;

  const int N = in_sizes[0] / HID;          // 100000
  const int E = in_sizes[1] / 2;            // 1600000
  const int L = in_sizes[4] / (HID * HID);  // 8
  const int R = (N + 511) >> BKSH;          // 196 buckets
  const int* row = ei;       // sources
  const int* col = ei + E;   // targets

  char* p = (char*)d_ws;
  auto alloc = [&](size_t bytes) {
    char* q = p;
    p += (bytes + 255) & ~(size_t)255;
    return q;
  };
  _Float16* x0h   = (_Float16*)alloc((size_t)N * HID * 2);  // raw h0 (alpha-mix)
  _Float16* gA    = (_Float16*)alloc((size_t)N * HID * 2);  // scaled g ping
  _Float16* gB    = (_Float16*)alloc((size_t)N * HID * 2);  // scaled g pong / raw h_L
  _Float16* sup16 = (_Float16*)alloc((size_t)N * HID * 2);
  _Float16* Wt    = (_Float16*)alloc((size_t)(L * 16384 + 16384 + 8192) * 2);
  int*    row_ptr = (int*)alloc((size_t)(N + 1) * 4);
  float*  dinv    = (float*)alloc((size_t)N * 4);
  int*    csr_src = (int*)alloc((size_t)E * 4);
  int*    tmp     = (int*)alloc((size_t)E * 4);
  int*    bcnt    = (int*)alloc((size_t)R * 4);
  int*    gb      = (int*)alloc((size_t)(R + 1) * 4);
  int*    gfront  = (int*)alloc((size_t)R * 4);
  (void)ws_size; (void)n_in; (void)out_size;

  const _Float16* Wt_in  = Wt + (size_t)L * 16384;
  const _Float16* Wt_out = Wt + (size_t)L * 16384 + 16384;

  hipMemsetAsync(bcnt, 0, (size_t)R * 4, stream);

  int nw = L * 16384 + 16384 + 8192;
  int nbe = (E + 4095) / 4096;  // 391
  k_wprep<<<(nw + 255) / 256, 256, 0, stream>>>(Wc, W_in, W_out, Wt, L);
  k_bhist<<<nbe, 512, 0, stream>>>(col, E, bcnt, R);
  k_scan196<<<1, 256, 0, stream>>>(bcnt, gb, gfront, R);
  k_partA<<<nbe, 512, 0, stream>>>(row, col, E, gfront, tmp, R);
  k_partB<<<R, 512, 0, stream>>>(tmp, gb, csr_src, row_ptr, dinv, N, E, R);

  int ggrid = (N + 127) / 128;  // 782
  int agrid = (N + 7) / 8;      // 12500

  // input projection: x(f32) @ W_in -> x0h raw + gA = dinv.*x0h
  k_mfma_gemm<128, true, true, true, true, true, true>
      <<<ggrid, 256, 0, stream>>>(x, Wt_in, b_in, dinv, gA, x0h, N);

  _Float16* cur = gA;
  _Float16* nxt = gB;
  for (int l = 0; l < L; ++l) {
    k_aggregate<<<agrid, 256, 0, stream>>>(cur, x0h, dinv, row_ptr, csr_src, sup16, N);
    if (l < L - 1) {
      k_mfma_gemm<128, true, false, false, true, true, false>
          <<<ggrid, 256, 0, stream>>>(sup16, Wt + (size_t)l * 16384, nullptr, dinv,
                                      nxt, nullptr, N);
    } else {
      // last layer: raw h (feeds output projection unscaled)
      k_mfma_gemm<128, true, false, false, true, false, true>
          <<<ggrid, 256, 0, stream>>>(sup16, Wt + (size_t)l * 16384, nullptr, nullptr,
                                      nullptr, nxt, N);
    }
    _Float16* t = cur; cur = nxt; nxt = t;
  }
  // output projection (fp32 out)
  k_mfma_gemm<64, false, true, false, false, false, true>
      <<<ggrid, 256, 0, stream>>>(cur, Wt_out, b_out, nullptr, nullptr, out, N);
}